// Round 9
// baseline (700.694 us; speedup 1.0000x reference)
//
#include <hip/hip_runtime.h>
#include <cstdint>

#define B_  4
#define S_  4096
#define D_  512

#define SCALEF 0.04419417382415922f   // 1/sqrt(512)
#define QSF    0.06375885f            // SCALEF * log2(e)  (pre-multiplied into Q)
#define MASK_FILLF -1e20f
#define MASKQ  -6.375885e18f          // MASK_FILL * SCALEF * log2(e)
#define FMAX2  17.312340f             // 12.0 * log2(e): fixed softmax max (log2 units)

typedef __attribute__((ext_vector_type(8))) short b16x8;   // 8 bf16 (4 VGPRs)
typedef __attribute__((ext_vector_type(4))) float f32x4;
typedef __attribute__((ext_vector_type(16))) float f32x16;

__device__ __forceinline__ unsigned short f2bf(float f) {
    unsigned int u = __builtin_bit_cast(unsigned int, f);
    u += 0x7fffu + ((u >> 16) & 1u);          // RNE
    return (unsigned short)(u >> 16);
}

__device__ __forceinline__ float exp2fast(float x) {
#if __has_builtin(__builtin_amdgcn_exp2f)
    return __builtin_amdgcn_exp2f(x);
#else
    return __expf(x * 0.69314718056f);
#endif
}

// global -> LDS direct copy, 16B per lane. LDS destination is wave-uniform base + lane*16.
__device__ __forceinline__ void gl_lds16(const void* gp, void* lp) {
    __builtin_amdgcn_global_load_lds(
        (const __attribute__((address_space(1))) unsigned int*)(uintptr_t)gp,
        (__attribute__((address_space(3))) unsigned int*)(uintptr_t)lp,
        16, 0, 0);
}

// ---------------------------------------------------------------- fused casts
// blocks 0..8191: X -> Xb (bf16).  blocks 8192..8959: W -> Wt[1536][512] bf16 transpose.
__global__ __launch_bounds__(256) void cast_fused_kernel(
    const float* __restrict__ X, unsigned short* __restrict__ Xb,
    const float* __restrict__ W, unsigned short* __restrict__ Wt) {
    __shared__ float t[32][33];
    int bid = blockIdx.x;
    if (bid < 8192) {
        int i = (bid * 256 + threadIdx.x) * 4;
        float4 v = *(const float4*)(X + i);
        ushort4 o;
        o.x = f2bf(v.x); o.y = f2bf(v.y); o.z = f2bf(v.z); o.w = f2bf(v.w);
        *(ushort4*)(Xb + i) = o;
    } else {
        int bb = bid - 8192;                  // 0..767
        int tx = threadIdx.x & 31, ty0 = threadIdx.x >> 5;
        int e0 = (bb % 48) * 32;              // 0..1535 (N dim)
        int d0 = (bb / 48) * 32;              // 0..511  (K dim)
#pragma unroll
        for (int p = 0; p < 4; ++p) {
            int ty = ty0 + p * 8;
            t[ty][tx] = W[(size_t)(d0 + ty) * 1536 + e0 + tx];
        }
        __syncthreads();
#pragma unroll
        for (int p = 0; p < 4; ++p) {
            int ty = ty0 + p * 8;
            Wt[(size_t)(e0 + ty) * 512 + d0 + tx] = f2bf(t[tx][ty]);
        }
    }
}

// ---------------------------------------------------------------- QKV GEMM (gemm_bt, 128x128, BK=32)
// Writes Q (pre-scaled by SCALE*log2e) row-major bf16; K AND V in transposed/
// panel layouts consumed directly from L2 by flash (no LDS staging there):
//   Kp[b*128+tile][chunk=d>>3][key=s&31][8 bf16]  (32KB per 32-key tile)
//   Vt[b*128+tile][d][key&31]                     (32KB per 32-key tile)
__global__ __launch_bounds__(256) void qkv_gemm_kernel(
    const unsigned short* __restrict__ Xb, const unsigned short* __restrict__ Wt,
    const float* __restrict__ bias,
    unsigned short* __restrict__ Qb, unsigned short* __restrict__ Kp,
    unsigned short* __restrict__ Vt) {
    __shared__ char lds[32768];
    const int tid = threadIdx.x, lane = tid & 63, wave = tid >> 6;
    const int quad = lane >> 4, kcol = lane & 15;
    const int wm = wave & 1, wn = wave >> 1;
    // XCD swizzle: all 12 col-panels of one row-panel share an XCD's L2
    const int lin = blockIdx.x;
    const int xcd = lin & 7;
    const int j = lin >> 3;                 // 0..191
    const int bx = (j & 15) * 8 + xcd;      // 0..127 row-panel
    const int by = j >> 4;                  // 0..11  col-panel
    const int row0 = bx * 128;
    const int col0 = by * 128;

    unsigned agl[2], bgl[2], lloc[2];
#pragma unroll
    for (int i = 0; i < 2; ++i) {
        int L = (wave * 2 + i) * 64 + lane;
        int r = L >> 2;
        int c = (L & 3) ^ ((r >> 1) & 3);
        agl[i] = (unsigned)((row0 + r) * 1024 + c * 16);
        bgl[i] = (unsigned)((col0 + r) * 1024 + c * 16);
        lloc[i] = (unsigned)(((wave * 2 + i) * 64) * 16);
    }

    f32x4 acc[4][4];
#pragma unroll
    for (int mt = 0; mt < 4; ++mt)
#pragma unroll
        for (int nt = 0; nt < 4; ++nt) acc[mt][nt] = (f32x4){0.f, 0.f, 0.f, 0.f};

    auto stage = [&](int kk) {
        char* la = lds + (kk & 1) * 16384;
        char* lb = la + 8192;
#pragma unroll
        for (int i = 0; i < 2; ++i) {
            gl_lds16((const char*)Xb + agl[i] + kk * 64, la + lloc[i]);
            gl_lds16((const char*)Wt + bgl[i] + kk * 64, lb + lloc[i]);
        }
    };

    stage(0);
    for (int kk = 0; kk < 16; ++kk) {
        __syncthreads();
        if (kk < 15) stage(kk + 1);
        const char* la = lds + (kk & 1) * 16384;
        const char* lb = la + 8192;
        b16x8 af[4], bfr[4];
#pragma unroll
        for (int mt = 0; mt < 4; ++mt) {
            int rr = wm * 64 + mt * 16 + kcol;
            af[mt] = *(const b16x8*)(la + rr * 64 + ((quad ^ ((rr >> 1) & 3)) << 4));
        }
#pragma unroll
        for (int nt = 0; nt < 4; ++nt) {
            int rr = wn * 64 + nt * 16 + kcol;
            bfr[nt] = *(const b16x8*)(lb + rr * 64 + ((quad ^ ((rr >> 1) & 3)) << 4));
        }
#pragma unroll
        for (int mt = 0; mt < 4; ++mt)
#pragma unroll
            for (int nt = 0; nt < 4; ++nt)
                acc[mt][nt] = __builtin_amdgcn_mfma_f32_16x16x32_bf16(af[mt], bfr[nt], acc[mt][nt], 0, 0, 0);
    }

    const int colbase = col0 + wn * 64;
    const int sec = colbase >> 9;  // 0:Q 1:K 2:V (uniform per wave)
    const int cbase = colbase & 511;
    float bv[4];
#pragma unroll
    for (int nt = 0; nt < 4; ++nt) bv[nt] = bias[colbase + nt * 16 + kcol];

    if (sec == 0) {
        // Q: row-major, pre-scaled for the flash softmax
#pragma unroll
        for (int mt = 0; mt < 4; ++mt) {
            int rg0 = row0 + wm * 64 + mt * 16 + quad * 4;
#pragma unroll
            for (int r = 0; r < 4; ++r) {
                size_t rowoff = (size_t)(rg0 + r) * 512;
#pragma unroll
                for (int nt = 0; nt < 4; ++nt)
                    Qb[rowoff + cbase + nt * 16 + kcol] = f2bf((acc[mt][nt][r] + bv[nt]) * QSF);
            }
        }
    } else if (sec == 1) {
        // K: write coalescable panels Kp[b*128+tile][d>>3][s&31][d&7]
#pragma unroll
        for (int mt = 0; mt < 4; ++mt) {
            int g0 = row0 + wm * 64 + mt * 16 + quad * 4;
#pragma unroll
            for (int r = 0; r < 4; ++r) {
                int g = g0 + r;
                int s = g & 4095;
                size_t pbase = ((size_t)((g >> 12) * 128 + (s >> 5))) * 32768 +
                               (size_t)(s & 31) * 16;
#pragma unroll
                for (int nt = 0; nt < 4; ++nt) {
                    int d = cbase + nt * 16 + kcol;
                    *(unsigned short*)((char*)Kp + pbase + (d >> 3) * 512 + (d & 7) * 2) =
                        f2bf(acc[mt][nt][r] + bv[nt]);
                }
            }
        }
    } else {
        // V: write transposed panels. Vt[pb][d][k], pb = b*128 + (s>>5), k = s&31.
#pragma unroll
        for (int mt = 0; mt < 4; ++mt) {
            int g0 = row0 + wm * 64 + mt * 16 + quad * 4;
#pragma unroll
            for (int r = 0; r < 4; ++r) {
                int g = g0 + r;
                int s = g & 4095;
                size_t pbase = (((size_t)(g >> 12) * 128 + (s >> 5)) << 14) + (s & 31);
#pragma unroll
                for (int nt = 0; nt < 4; ++nt) {
                    int d = cbase + nt * 16 + kcol;
                    Vt[pbase + (size_t)d * 32] = f2bf(acc[mt][nt][r] + bv[nt]);
                }
            }
        }
    }
}

// ---------------------------------------------------------------- flash attention v16 (= v15 + correct LDS size)
// v13 loop structure EXACTLY (one A barrier per 64-key interval, QK || PV
// overlap, fused 1/l epilogue) with K-STAGING REMOVED: producers read K
// fragments directly from L2 via the coalesced Kp panel layout (1KB
// contiguous per wave-load), just as consumers already do for Vt. Deletes:
// consumer staging instrs, the barrier-A vmcnt staging drain, and the 8-way
// kf LDS bank conflicts (K rows were 1KB -> bank index ignored the row).
// 256 blocks x 384 threads (6 waves), BM=64, NI=64 intervals, 1 block/CU.
// LDS: P only = 2 parities x 2 halves x 5120 B = 20480 B (v15 bug: allocated
// 10240 -> parity-1 OOB). lbuf reuses parity-0 (dead after F).
__global__ __launch_bounds__(384, 2) void flash_kernel(
    const unsigned short* __restrict__ Qb, const unsigned short* __restrict__ Kp,
    const unsigned short* __restrict__ Vt, const int* __restrict__ maskG,
    float* __restrict__ Out) {
    extern __shared__ char smem[];
    const int tid = threadIdx.x;
    const int lane = tid & 63;
    const int wave = tid >> 6;
    const int lin = blockIdx.x;
    const int b = lin & 3;          // batch; XCDs {b, b+4} share this batch's K/V
    const int qrow0 = (lin >> 2) * 64;
    const int NI = 64;              // intervals of 64 keys (2 sub-tiles of 32)

    unsigned short* Pb = (unsigned short*)smem;   // [parity(2)][half(2)] x 5120B = 20480B
    float* lbuf = (float*)smem;                   // 64 f32 (parity-0, dead after F)

    const char* kpbase = (const char*)Kp + (size_t)b * 128 * 32768;
    const char* vgbase = (const char*)Vt + (size_t)b * 128 * 32768;
    const int* mrow = maskG + b * S_;

    if (wave < 2) {
        // ========== PRODUCER: QK (32x32x16, K direct from L2) + softmax ==========
        const int keyrow = lane & 31;    // key index within sub-tile
        const int hh = lane >> 5;        // k-half

        // Q fragments: A[m=lane&31][k=hh*8+j] per 16-wide k-step; 32 steps = 128 regs
        b16x8 qf[32];
        {
            const unsigned short* qptr =
                Qb + (size_t)(b * S_ + qrow0 + wave * 32 + keyrow) * D_ + hh * 8;
#pragma unroll
            for (int ks = 0; ks < 32; ++ks) qf[ks] = *(const b16x8*)(qptr + ks * 16);
        }
        float lsum16[16];
#pragma unroll
        for (int r = 0; r < 16; ++r) lsum16[r] = 0.f;

        for (int it = 0; it < NI; ++it) {
            __syncthreads();  // A(it): P parity (it&1) free (consumer reads drained)
            unsigned short* Ppar = Pb + (it & 1) * 5120;
#pragma unroll
            for (int h = 0; h < 2; ++h) {
                const bool um = mrow[it * 64 + h * 32 + keyrow] != 0;
                // K tile (it*2+h): panel reads, 1KB contiguous per wave-load
                const char* ktile = kpbase + (size_t)(it * 2 + h) * 32768;
                f32x16 sA, sB;
#pragma unroll
                for (int i = 0; i < 16; ++i) { sA[i] = 0.f; sB[i] = 0.f; }
#pragma unroll
                for (int ks = 0; ks < 32; ++ks) {
                    b16x8 kf = *(const b16x8*)(ktile + (ks * 2 + hh) * 512 + keyrow * 16);
                    if (ks & 1) sB = __builtin_amdgcn_mfma_f32_32x32x16_bf16(qf[ks], kf, sB, 0, 0, 0);
                    else        sA = __builtin_amdgcn_mfma_f32_32x32x16_bf16(qf[ks], kf, sA, 0, 0, 0);
                }
                // softmax: this lane holds col(key)=keyrow, rows (r&3)+8*(r>>2)+4*hh
                unsigned short* Pcur = Ppar + h * 2560;
#pragma unroll
                for (int r = 0; r < 16; ++r) {
                    float sv = sA[r] + sB[r];
                    float lg = um ? sv : MASKQ;       // mask BEFORE scale (Q prescaled)
                    float ex = exp2fast(lg - FMAX2);
                    lsum16[r] += ex;
                    int row = (r & 3) + 8 * (r >> 2) + 4 * hh + wave * 32;
                    Pcur[row * 40 + keyrow] = f2bf(ex);
                }
            }
        }
        __syncthreads();  // F: matches consumer count; P(NI-1) visible

        // epilogue: reduce l over the 32 key-lanes, write 1/l into LDS (parity-0 dead)
#pragma unroll
        for (int r = 0; r < 16; ++r) {
            float l = lsum16[r];
            l += __shfl_xor(l, 1);
            l += __shfl_xor(l, 2);
            l += __shfl_xor(l, 4);
            l += __shfl_xor(l, 8);
            l += __shfl_xor(l, 16);
            if ((lane & 31) == 0) {
                int row = (r & 3) + 8 * (r >> 2) + 4 * hh + wave * 32;
                lbuf[row] = 1.0f / l;
            }
        }
        __syncthreads();  // L: 1/l visible
    } else {
        // ========== CONSUMER: PV only (d-sliced), V direct from L2 ==========
        const int ws = wave - 2;         // 0..3
        const int dw = ws * 128;         // d-slice
        const int quad = lane >> 4;
        const int kcol = lane & 15;

        f32x4 o[4][8];
#pragma unroll
        for (int m = 0; m < 4; ++m)
#pragma unroll
            for (int n = 0; n < 8; ++n) o[m][n] = (f32x4){0.f, 0.f, 0.f, 0.f};

        for (int it = 0; it < NI; ++it) {
            __syncthreads();  // A(it)

            if (it > 0) {
                const unsigned short* Ppar = Pb + ((it ^ 1) & 1) * 5120;   // parity it-1
                // ---- half a of PV(it-1)
                b16x8 vf[8], pf[4];
                const char* vtile = vgbase + (size_t)((it - 1) * 2) * 32768;
#pragma unroll
                for (int n = 0; n < 8; ++n)
                    vf[n] = *(const b16x8*)(vtile + (size_t)(dw + n * 16 + kcol) * 64 + quad * 16);
#pragma unroll
                for (int m = 0; m < 4; ++m)
                    pf[m] = *(const b16x8*)((const char*)Ppar + (m * 16 + kcol) * 80 + quad * 16);
#pragma unroll
                for (int m = 0; m < 4; ++m)
#pragma unroll
                    for (int n = 0; n < 8; ++n)
                        o[m][n] = __builtin_amdgcn_mfma_f32_16x16x32_bf16(pf[m], vf[n], o[m][n], 0, 0, 0);

                // ---- half b of PV(it-1)
                const char* vtileb = vgbase + (size_t)((it - 1) * 2 + 1) * 32768;
#pragma unroll
                for (int n = 0; n < 8; ++n)
                    vf[n] = *(const b16x8*)(vtileb + (size_t)(dw + n * 16 + kcol) * 64 + quad * 16);
                const unsigned short* Pcb = Ppar + 2560;
#pragma unroll
                for (int m = 0; m < 4; ++m)
                    pf[m] = *(const b16x8*)((const char*)Pcb + (m * 16 + kcol) * 80 + quad * 16);
#pragma unroll
                for (int m = 0; m < 4; ++m)
#pragma unroll
                    for (int n = 0; n < 8; ++n)
                        o[m][n] = __builtin_amdgcn_mfma_f32_16x16x32_bf16(pf[m], vf[n], o[m][n], 0, 0, 0);
            }
        }
        __syncthreads();  // F: P(NI-1) visible

        {  // tail PV for interval NI-1 (parity 1 buffers — disjoint from lbuf)
            const unsigned short* Ppar = Pb + ((NI - 1) & 1) * 5120;
#pragma unroll
            for (int h = 0; h < 2; ++h) {
                const char* vtile = vgbase + (size_t)((NI - 1) * 2 + h) * 32768;
                b16x8 vf[8], pf[4];
#pragma unroll
                for (int n = 0; n < 8; ++n)
                    vf[n] = *(const b16x8*)(vtile + (size_t)(dw + n * 16 + kcol) * 64 + quad * 16);
                const unsigned short* Pcur = Ppar + h * 2560;
#pragma unroll
                for (int m = 0; m < 4; ++m)
                    pf[m] = *(const b16x8*)((const char*)Pcur + (m * 16 + kcol) * 80 + quad * 16);
#pragma unroll
                for (int m = 0; m < 4; ++m)
#pragma unroll
                    for (int n = 0; n < 8; ++n)
                        o[m][n] = __builtin_amdgcn_mfma_f32_16x16x32_bf16(pf[m], vf[n], o[m][n], 0, 0, 0);
            }
        }
        __syncthreads();  // L: 1/l visible

        // epilogue: scale by 1/l and write FINAL output
#pragma unroll
        for (int m = 0; m < 4; ++m) {
            f32x4 lv = *(const f32x4*)(lbuf + m * 16 + quad * 4);
#pragma unroll
            for (int r = 0; r < 4; ++r) {
                size_t off = ((size_t)b * S_ + qrow0 + m * 16 + quad * 4 + r) * D_ + dw + kcol;
#pragma unroll
                for (int n = 0; n < 8; ++n) Out[off + n * 16] = o[m][n][r] * lv[r];
            }
        }
    }
}

// ---------------------------------------------------------------- host
extern "C" void kernel_launch(void* const* d_in, const int* in_sizes, int n_in,
                              void* d_out, int out_size, void* d_ws, size_t ws_size,
                              hipStream_t stream) {
    const float* X = (const float*)d_in[0];       // [4,4096,512]
    const float* W = (const float*)d_in[1];       // [512,1536]
    const float* bias = (const float*)d_in[2];    // [1536]
    const int* mask = (const int*)d_in[3];        // [4,1,4096]
    float* out = (float*)d_out;

    char* w = (char*)d_ws;
    unsigned short* Xb = (unsigned short*)w;  w += (size_t)16384 * 512 * 2;   // 16 MB
    unsigned short* Wt = (unsigned short*)w;  w += (size_t)1536 * 512 * 2;    // 1.5 MB
    unsigned short* Qb = (unsigned short*)w;  w += (size_t)16384 * 512 * 2;   // 16 MB
    unsigned short* Kp = (unsigned short*)w;  w += (size_t)16384 * 512 * 2;   // 16 MB (panels)
    unsigned short* Vt = (unsigned short*)w;  w += (size_t)16384 * 512 * 2;   // 16 MB (panels)

    cast_fused_kernel<<<8960, 256, 0, stream>>>(X, Xb, W, Wt);
    qkv_gemm_kernel<<<1536, 256, 0, stream>>>(Xb, Wt, bias, Qb, Kp, Vt);

    (void)hipFuncSetAttribute((const void*)flash_kernel,
                              hipFuncAttributeMaxDynamicSharedMemorySize, 20480);
    flash_kernel<<<256, 384, 20480, stream>>>(Qb, Kp, Vt, mask, out);
}